// Round 13
// baseline (799.679 us; speedup 1.0000x reference)
//
#include <hip/hip_runtime.h>
#include <math.h>

// ---------------------------------------------------------------------------
// JTNN decoder forward on MI355X.  v13:
//  * k_gru: 1 msg row / 256-thread block, grid 1024 -> 4 independent
//    blocks/CU (v12 ganged 16 waves on 3 barriers at 1 block/CU; every wave
//    waited on the slowest gather with nothing else resident). A-tile row =
//    neighbor index (one 8-frag A covers the whole r-gate); z/h GEMMs use
//    broadcast-row A (M-waste irrelevant at 0.4% MfmaUtil); barriers span 4
//    waves; cross-block overlap hides gather/launch latency.
//  * Fragment-major weights (v12 k_rep), x-side gate tables (v7),
//    merged heads w/ single-buffer LDS B-tiles (v12, 161us validated).
//  * MFMA layouts (validated R2-R12): A[m=lane&15][k=32*kb+8*q+j],
//    B[k][n=lane&15], D[row=4*q+i][col=lane&15].
// ---------------------------------------------------------------------------

namespace {

constexpr int T_  = 32;
constexpr int N_  = 1024;
constexpr int H_  = 256;
constexpr int NB_ = 15;
constexpr int E_  = T_ * N_;      // 32768
constexpr int B_  = 256;
constexpr int PREDB_ = (B_ + E_) / 64;   // 516
constexpr int STOPB_ = (E_ + B_) / 64;   // 516

typedef unsigned short u16;
typedef unsigned int   u32;
typedef unsigned int  uix4  __attribute__((ext_vector_type(4)));
typedef __bf16        bf16x8 __attribute__((ext_vector_type(8)));
typedef float         f32x4  __attribute__((ext_vector_type(4)));

__device__ __forceinline__ float sig_(float x){ return 1.f / (1.f + __expf(-x)); }

__device__ __forceinline__ float b2f(u16 u){
  union { u32 i; float f; } v; v.i = ((u32)u) << 16; return v.f;
}
__device__ __forceinline__ u16 f2b(float f){
  union { float f; u32 i; } v; v.f = f;
  const u32 r = v.i + 0x7fffu + ((v.i >> 16) & 1u);
  return (u16)(r >> 16);
}
__device__ __forceinline__ f32x4 mfma16(uix4 a, uix4 b, f32x4 c){
  return __builtin_amdgcn_mfma_f32_16x16x32_bf16(
      __builtin_bit_cast(bf16x8, a), __builtin_bit_cast(bf16x8, b), c, 0, 0, 0);
}

// ---- fp32 -> bf16 conversion (once per launch) ----------------------------
__global__ __launch_bounds__(256) void k_cvt(
    const float* __restrict__ emb, const float* __restrict__ xt,
    const float* __restrict__ Ww,  const float* __restrict__ Wo,
    const float* __restrict__ Ui,  const float* __restrict__ Uw,
    const float* __restrict__ Wz,  const float* __restrict__ Wr,
    const float* __restrict__ Ur,  const float* __restrict__ Wh,
    u16* __restrict__ o_emb, u16* __restrict__ o_xt, u16* __restrict__ o_Ww,
    u16* __restrict__ o_Wo,  u16* __restrict__ o_Ui, u16* __restrict__ o_Uw,
    u16* __restrict__ o_Wz,  u16* __restrict__ o_Wr, u16* __restrict__ o_Ur,
    u16* __restrict__ o_Wh)
{
  int i = blockIdx.x * 256 + threadIdx.x;
  if (i < 204800){ o_emb[i] = f2b(emb[i]); return; }  i -= 204800;
  if (i <  32768){ o_xt[i]  = f2b(xt[i]);  return; }  i -=  32768;
  if (i <  98304){ o_Ww[i]  = f2b(Ww[i]);  return; }  i -=  98304;
  if (i < 204800){ o_Wo[i]  = f2b(Wo[i]);  return; }  i -= 204800;
  if (i < 131072){ o_Ui[i]  = f2b(Ui[i]);  return; }  i -= 131072;
  if (i <  98304){ o_Uw[i]  = f2b(Uw[i]);  return; }  i -=  98304;
  if (i < 131072){ o_Wz[i]  = f2b(Wz[i]);  return; }  i -= 131072;
  if (i <  65536){ o_Wr[i]  = f2b(Wr[i]);  return; }  i -=  65536;
  if (i <  65536){ o_Ur[i]  = f2b(Ur[i]);  return; }  i -=  65536;
  if (i < 131072){ o_Wh[i]  = f2b(Wh[i]); }
}

// ---- fragment-major repack: Ur, Wz sum_h-half, Wh gated-half --------------
__global__ __launch_bounds__(256) void k_rep(
    const u16* __restrict__ Ur16, const u16* __restrict__ Wz16,
    const u16* __restrict__ Wh16,
    u16* __restrict__ UrF, u16* __restrict__ WzF, u16* __restrict__ WhF)
{
  const int idx = blockIdx.x * 256 + threadIdx.x;
  const int mat = idx >> 13, r = idx & 8191;
  const int ctkb = r >> 6, lane = r & 63;
  const int ct = ctkb >> 3, kb = ctkb & 7;
  const int q = lane >> 4, m = lane & 15;
  const int col = ct * 16 + m;
  const u16* src;
  u16* dst;
  if (mat == 0){ src = Ur16 + (size_t)col*256 +       kb*32 + q*8; dst = UrF; }
  else if (mat == 1){ src = Wz16 + (size_t)col*512 + 256 + kb*32 + q*8; dst = WzF; }
  else { src = Wh16 + (size_t)col*512 + 256 + kb*32 + q*8; dst = WhF; }
  *(uix4*)(dst + (size_t)r * 8) = *(const uix4*)src;
}

// ---- init ------------------------------------------------------------------
__global__ __launch_bounds__(256) void k_init(float* __restrict__ acc,
                                              u16* __restrict__ hb16){
  const int tid = threadIdx.x;
  if (tid < 16) acc[tid] = 0.f;
  hb16[(size_t)E_ * H_ + tid] = 0;   // row E = zero pad slot
}

// ---- precompute x-side gate tables: 800x256 fp32, bias folded -------------
__global__ __launch_bounds__(256) void k_tab(
    const u16* __restrict__ emb16,
    const u16* __restrict__ Wr16, const float* __restrict__ Wrb,
    const u16* __restrict__ Wz16, const float* __restrict__ Wzb,
    const u16* __restrict__ Wh16, const float* __restrict__ Whb,
    float* __restrict__ xrtab, float* __restrict__ xztab,
    float* __restrict__ xhtab)
{
  const int tid = threadIdx.x;
  const int w = tid >> 6, ln = tid & 63, q = ln >> 4, m = ln & 15;
  const int r0 = blockIdx.x * 16;

  uix4 Ae[8];
  {
    const u16* ep = emb16 + (size_t)(r0 + m) * 256 + q * 8;
    #pragma unroll
    for (int kb = 0; kb < 8; ++kb) Ae[kb] = *(const uix4*)(ep + kb * 32);
  }
  #pragma unroll
  for (int nt = 0; nt < 4; ++nt){
    const int col = w * 64 + nt * 16 + m;
    f32x4 ar = {0.f,0.f,0.f,0.f}, az = {0.f,0.f,0.f,0.f}, ah = {0.f,0.f,0.f,0.f};
    const u16* br = Wr16 + (size_t)col * 256 + q * 8;
    const u16* bz = Wz16 + (size_t)col * 512 + q * 8;   // x-part of Wz
    const u16* bh = Wh16 + (size_t)col * 512 + q * 8;   // x-part of Wh
    #pragma unroll
    for (int kb = 0; kb < 8; ++kb){
      ar = mfma16(Ae[kb], *(const uix4*)(br + kb*32), ar);
      az = mfma16(Ae[kb], *(const uix4*)(bz + kb*32), az);
      ah = mfma16(Ae[kb], *(const uix4*)(bh + kb*32), ah);
    }
    const float rb = Wrb[col], zb = Wzb[col], hb = Whb[col];
    #pragma unroll
    for (int i = 0; i < 4; ++i){
      const size_t o = (size_t)(r0 + 4*q + i) * 256 + col;
      xrtab[o] = ar[i] + rb;
      xztab[o] = az[i] + zb;
      xhtab[o] = ah[i] + hb;
    }
  }
}

// ---- one GRU scan step: 1 msg row/block, 256 threads, grid 1024 -----------
// A-tile row = neighbor index (nb 15 = zero pad row E); one 8-frag A covers
// the whole r-gate. Wave w owns cols [w*64,(w+1)*64) = global ct w*4..w*4+3.
// D row 4q+i = nb; ga/su reduced over q via shfl_xor(16/32) (col dep on m only).
__global__ __launch_bounds__(256, 4) void k_gru(
    const u16* __restrict__ UrF, const u16* __restrict__ WzF,
    const u16* __restrict__ WhF,
    const float* __restrict__ xrtab, const float* __restrict__ xztab,
    const float* __restrict__ xhtab,
    const int* __restrict__ word_ids, const int* __restrict__ h_nei,
    u16* __restrict__ hb16, int t)
{
  __shared__ __align__(16) u16 hn[16 * 264];   // 16 neighbor rows, padded
  __shared__ __align__(16) u16 sh[264];        // sum_h vector
  __shared__ __align__(16) u16 gl[264];        // gated vector
  __shared__ int s_hidx[16];

  const int tid = threadIdx.x;
  const int w = tid >> 6, ln = tid & 63, q = ln >> 4, m = ln & 15;
  const int row = t * N_ + blockIdx.x;         // this block's message row

  if (tid < 16)
    s_hidx[tid] = (tid < NB_) ? h_nei[row * NB_ + tid] : E_;
  const int wid = word_ids[row];               // wave-uniform scalar load
  __syncthreads();

  // stage 16 neighbor rows (512B coalesced each; 2 chunks/thread)
  #pragma unroll
  for (int it = 0; it < 2; ++it){
    const int task = it * 256 + tid;
    const int r = task >> 5, ch = task & 31;
    *(uix4*)(&hn[r*264 + ch*8]) =
        *(const uix4*)(hb16 + (size_t)s_hidx[r]*256 + ch*8);
  }
  __syncthreads();

  // A-frags: A row = nb (shared across all 4 col-tiles)
  uix4 Ah[8];
  #pragma unroll
  for (int kb = 0; kb < 8; ++kb)
    Ah[kb] = *(const uix4*)(&hn[m*264 + kb*32 + q*8]);

  // r-gate per col-tile; extract ga/su; reduce over q
  float ga[4], su[4];
  #pragma unroll
  for (int ct = 0; ct < 4; ++ct){
    const int col = w*64 + ct*16 + m;
    const float xr = xrtab[(size_t)wid * 256 + col];
    f32x4 a = {xr, xr, xr, xr};
    const u16* bp = UrF + (size_t)((w*4 + ct)*8) * 512 + ln * 8;
    #pragma unroll
    for (int kb = 0; kb < 8; ++kb) a = mfma16(Ah[kb], *(const uix4*)(bp + kb*512), a);
    float pg = 0.f, ps = 0.f;
    #pragma unroll
    for (int i = 0; i < 4; ++i){
      const float hv = b2f(hn[(4*q + i)*264 + col]);
      pg += sig_(a[i]) * hv;
      ps += hv;
    }
    pg += __shfl_xor(pg, 16, 64); pg += __shfl_xor(pg, 32, 64);
    ps += __shfl_xor(ps, 16, 64); ps += __shfl_xor(ps, 32, 64);
    ga[ct] = pg; su[ct] = ps;
  }
  if (q == 0){
    #pragma unroll
    for (int ct = 0; ct < 4; ++ct){
      sh[w*64 + ct*16 + m] = f2b(su[ct]);
      gl[w*64 + ct*16 + m] = f2b(ga[ct]);
    }
  }
  __syncthreads();

  // z / h~ GEMMs: broadcast-row A (all 16 M-rows = the message's vector)
  uix4 As[8], Ag[8];
  #pragma unroll
  for (int kb = 0; kb < 8; ++kb){
    As[kb] = *(const uix4*)(&sh[kb*32 + q*8]);
    Ag[kb] = *(const uix4*)(&gl[kb*32 + q*8]);
  }
  #pragma unroll
  for (int ct = 0; ct < 4; ++ct){
    const int col = w*64 + ct*16 + m;
    const float xz = xztab[(size_t)wid * 256 + col];
    const float xh = xhtab[(size_t)wid * 256 + col];
    f32x4 az = {xz, xz, xz, xz};
    f32x4 ah = {xh, xh, xh, xh};
    const u16* zb = WzF + (size_t)((w*4 + ct)*8) * 512 + ln * 8;
    const u16* hb = WhF + (size_t)((w*4 + ct)*8) * 512 + ln * 8;
    #pragma unroll
    for (int kb = 0; kb < 8; ++kb) az = mfma16(As[kb], *(const uix4*)(zb + kb*512), az);
    #pragma unroll
    for (int kb = 0; kb < 8; ++kb) ah = mfma16(Ag[kb], *(const uix4*)(hb + kb*512), ah);
    if (q == 0){
      const float z  = sig_(az[0]);
      const float ht = tanhf(ah[0]);
      const float nh = (1.f - z) * su[ct] + z * ht;
      hb16[(size_t)row * 256 + col] = f2b(nh);
    }
  }
}

// ---- merged heads (v12 validated) -----------------------------------------
struct PredSm {
  u16   hd[4][16][264];
  u16   bt[16][392];
  int   tgt[64];
  float mask[64];
  float nll[64], hit[64], msk[64];
};
struct StopSm {
  u16   so[64][264];
  u16   bt[16][392];
  int   oidx[64][NB_];
  int   wid[64], ctx[64];
  float tgt[64];
  float b0[64], b1[64];
};
constexpr size_t SMU_ = sizeof(StopSm) > sizeof(PredSm) ? sizeof(StopSm)
                                                        : sizeof(PredSm);

__device__ void pred_body(int bid, char* smraw,
    const u16* __restrict__ hb16, const u16* __restrict__ Ww16,
    const float* __restrict__ Wb, const u16* __restrict__ Wo16,
    const float* __restrict__ Wob, const u16* __restrict__ xt16,
    const int* __restrict__ contexts, const int* __restrict__ pred_targets,
    const int* __restrict__ direction, const int* __restrict__ root_word_ids,
    float* __restrict__ accum)
{
  PredSm& sm = *(PredSm*)smraw;
  const int tid = threadIdx.x;
  const int p0  = bid * 64;
  const int w = tid >> 6, ln = tid & 63, q = ln >> 4, m = ln & 15;
  const int r0 = w * 16;

  if (tid < 64){
    const int p = p0 + tid;
    int tg; float mk;
    if (p < B_){ tg = root_word_ids[p]; mk = 1.f; }
    else { tg = pred_targets[p - B_]; mk = (float)direction[p - B_]; }
    sm.tgt[tid] = tg; sm.mask[tid] = mk;
  }
  const int p    = p0 + r0 + m;
  const int hrow = (p < B_) ? E_ : (p - B_);
  const int ctx  = (p < B_) ? p  : contexts[p - B_];

  uix4 A1[12];
  {
    const u16* hp = hb16 + (size_t)hrow * 256 + q * 8;
    #pragma unroll
    for (int j = 0; j < 8; ++j) A1[j] = *(const uix4*)(hp + j * 32);
    const u16* xp = xt16 + (size_t)ctx * 128 + q * 8;
    #pragma unroll
    for (int j = 0; j < 4; ++j) A1[8 + j] = *(const uix4*)(xp + j * 32);
  }

  {
    #pragma unroll
    for (int j = 0; j < 3; ++j){
      const int i = j*256 + tid, r = i / 48, c = i % 48;
      *(uix4*)(&sm.bt[r][c*8]) = *(const uix4*)(Ww16 + (size_t)i*8);
    }
  }
  __syncthreads();
  for (int t = 0; t < 16; ++t){
    uix4 pf[3];
    if (t < 15){
      const u16* src = Ww16 + (size_t)(t+1)*16*384;
      #pragma unroll
      for (int j = 0; j < 3; ++j)
        pf[j] = *(const uix4*)(src + (size_t)(j*256 + tid)*8);
    }
    f32x4 acc = {0.f, 0.f, 0.f, 0.f};
    const u16* bp = &sm.bt[m][q*8];
    #pragma unroll
    for (int j = 0; j < 12; ++j) acc = mfma16(A1[j], *(const uix4*)(bp + j*32), acc);
    const float bias = Wb[t*16 + m];
    #pragma unroll
    for (int i = 0; i < 4; ++i)
      sm.hd[w][q*4 + i][t*16 + m] = f2b(fmaxf(acc[i] + bias, 0.f));
    __syncthreads();
    if (t < 15){
      #pragma unroll
      for (int j = 0; j < 3; ++j){
        const int i = j*256 + tid, r = i / 48, c = i % 48;
        *(uix4*)(&sm.bt[r][c*8]) = pf[j];
      }
      __syncthreads();
    }
  }

  uix4 A2[8];
  #pragma unroll
  for (int j = 0; j < 8; ++j) A2[j] = *(const uix4*)(&sm.hd[w][m][j*32 + q*8]);

  int tgtc[4];
  #pragma unroll
  for (int i = 0; i < 4; ++i) tgtc[i] = sm.tgt[r0 + q*4 + i];
  float lrun[4], amax[4], tval[4]; int aidx[4];
  #pragma unroll
  for (int i = 0; i < 4; ++i){
    lrun[i] = 0.f; amax[i] = -1e30f; tval[i] = -1e30f; aidx[i] = 0;
  }

  {
    #pragma unroll
    for (int j = 0; j < 2; ++j){
      const int i = j*256 + tid, r = i >> 5, c = i & 31;
      *(uix4*)(&sm.bt[r][c*8]) = *(const uix4*)(Wo16 + (size_t)i*8);
    }
  }
  __syncthreads();
  for (int t = 0; t < 50; ++t){
    uix4 pf[2];
    if (t < 49){
      const u16* src = Wo16 + (size_t)(t+1)*16*256;
      #pragma unroll
      for (int j = 0; j < 2; ++j)
        pf[j] = *(const uix4*)(src + (size_t)(j*256 + tid)*8);
    }
    f32x4 acc = {0.f, 0.f, 0.f, 0.f};
    const u16* bp = &sm.bt[m][q*8];
    #pragma unroll
    for (int j = 0; j < 8; ++j) acc = mfma16(A2[j], *(const uix4*)(bp + j*32), acc);
    const int c = t*16 + m;
    const float bias = Wob[c];
    #pragma unroll
    for (int i = 0; i < 4; ++i){
      const float v = acc[i] + bias;
      if (c == tgtc[i]) tval[i] = v;
      if (v > amax[i]){ amax[i] = v; aidx[i] = c; }
      lrun[i] += __expf(v);
    }
    __syncthreads();
    if (t < 49){
      #pragma unroll
      for (int j = 0; j < 2; ++j){
        const int i = j*256 + tid, r = i >> 5, cc = i & 31;
        *(uix4*)(&sm.bt[r][cc*8]) = pf[j];
      }
      __syncthreads();
    }
  }
  #pragma unroll
  for (int msk = 1; msk < 16; msk <<= 1){
    #pragma unroll
    for (int i = 0; i < 4; ++i){
      lrun[i] += __shfl_xor(lrun[i], msk, 64);
      const float oa = __shfl_xor(amax[i], msk, 64);
      const int   oi = __shfl_xor(aidx[i], msk, 64);
      if (oa > amax[i] || (oa == amax[i] && oi < aidx[i])){ amax[i] = oa; aidx[i] = oi; }
      tval[i] = fmaxf(tval[i], __shfl_xor(tval[i], msk, 64));
    }
  }
  if (m == 0){
    #pragma unroll
    for (int i = 0; i < 4; ++i){
      const int r = r0 + q*4 + i;
      const float mk  = sm.mask[r];
      const float nll = __logf(lrun[i]) - tval[i];
      sm.nll[r] = nll * mk;
      sm.hit[r] = (aidx[i] == tgtc[i]) ? mk : 0.f;
      sm.msk[r] = mk;
    }
  }
  __syncthreads();
  if (tid < 64){
    float a = sm.nll[tid], b = sm.hit[tid], c2 = sm.msk[tid];
    #pragma unroll
    for (int off = 32; off > 0; off >>= 1){
      a += __shfl_down(a, off, 64); b += __shfl_down(b, off, 64); c2 += __shfl_down(c2, off, 64);
    }
    if (tid == 0){
      atomicAdd(&accum[0], a); atomicAdd(&accum[1], b); atomicAdd(&accum[2], c2);
    }
  }
}

__device__ void stop_body(int bid, char* smraw,
    const u16* __restrict__ hb16, const u16* __restrict__ emb16,
    const u16* __restrict__ Ui16, const float* __restrict__ Uib,
    const u16* __restrict__ Uw16, const float* __restrict__ Ub,
    const float* __restrict__ Uo, const float* __restrict__ Uob,
    const u16* __restrict__ xt16,
    const int* __restrict__ word_ids, const int* __restrict__ o_nei,
    const int* __restrict__ contexts, const int* __restrict__ direction,
    const int* __restrict__ root_word_ids, const int* __restrict__ root_o_idx,
    float* __restrict__ accum)
{
  StopSm& sm = *(StopSm*)smraw;
  const int tid = threadIdx.x;
  const int p0  = bid * 64;
  const int w = tid >> 6, ln = tid & 63, q = ln >> 4, m = ln & 15;
  const int r0 = w * 16;

  if (tid < 64){
    const int s = p0 + tid;
    if (s < E_){ sm.wid[tid] = word_ids[s]; sm.ctx[tid] = contexts[s];
                 sm.tgt[tid] = (float)direction[s]; }
    else { const int b = s - E_; sm.wid[tid] = root_word_ids[b]; sm.ctx[tid] = b;
           sm.tgt[tid] = 0.f; }
  }
  for (int k = tid; k < 64 * NB_; k += 256){
    const int r = k / NB_, nb = k % NB_;
    const int s = p0 + r;
    sm.oidx[r][nb] = (s < E_) ? o_nei[(size_t)s * NB_ + nb]
                              : root_o_idx[(size_t)(s - E_) * NB_ + nb];
  }
  __syncthreads();

  for (int it = 0; it < 4; ++it){
    const int task = it * 256 + tid;
    const int row = task >> 4, sl = task & 15;
    float a[16];
    #pragma unroll
    for (int c = 0; c < 16; ++c) a[c] = 0.f;
    #pragma unroll
    for (int nb = 0; nb < NB_; ++nb){
      const u16* p = hb16 + (size_t)sm.oidx[row][nb] * 256 + sl * 16;
      const uix4 v0 = *(const uix4*)(p);
      const uix4 v1 = *(const uix4*)(p + 8);
      #pragma unroll
      for (int c = 0; c < 4; ++c){
        a[2*c]     += b2f((u16)(v0[c] & 0xffffu));
        a[2*c + 1] += b2f((u16)(v0[c] >> 16));
        a[8 + 2*c] += b2f((u16)(v1[c] & 0xffffu));
        a[9 + 2*c] += b2f((u16)(v1[c] >> 16));
      }
    }
    uix4 o0, o1;
    #pragma unroll
    for (int c = 0; c < 4; ++c){
      o0[c] = (u32)f2b(a[2*c])   | ((u32)f2b(a[2*c+1]) << 16);
      o1[c] = (u32)f2b(a[8+2*c]) | ((u32)f2b(a[9+2*c]) << 16);
    }
    *(uix4*)(&sm.so[row][sl*16])     = o0;
    *(uix4*)(&sm.so[row][sl*16 + 8]) = o1;
  }
  __syncthreads();

  uix4 A1[16];
  {
    const u16* ep = emb16 + (size_t)sm.wid[r0 + m] * 256 + q * 8;
    #pragma unroll
    for (int j = 0; j < 8; ++j) A1[j] = *(const uix4*)(ep + j * 32);
    #pragma unroll
    for (int j = 0; j < 8; ++j) A1[8 + j] = *(const uix4*)(&sm.so[r0 + m][j*32 + q*8]);
  }
  __syncthreads();

  for (int t = 0; t < 16; ++t){
    f32x4 acc = {0.f, 0.f, 0.f, 0.f};
    const u16* bp = Ui16 + (size_t)(t*16 + m) * 512 + q * 8;
    #pragma unroll
    for (int j = 0; j < 16; ++j) acc = mfma16(A1[j], *(const uix4*)(bp + j*32), acc);
    const float bias = Uib[t*16 + m];
    #pragma unroll
    for (int i = 0; i < 4; ++i)
      sm.so[r0 + q*4 + i][t*16 + m] = f2b(fmaxf(acc[i] + bias, 0.f));
  }
  __syncthreads();

  uix4 A2[12];
  {
    #pragma unroll
    for (int j = 0; j < 8; ++j) A2[j] = *(const uix4*)(&sm.so[r0 + m][j*32 + q*8]);
    const u16* xp = xt16 + (size_t)sm.ctx[r0 + m] * 128 + q * 8;
    #pragma unroll
    for (int j = 0; j < 4; ++j) A2[8 + j] = *(const uix4*)(xp + j * 32);
  }
  float sp[4] = {0.f, 0.f, 0.f, 0.f};
  {
    #pragma unroll
    for (int j = 0; j < 3; ++j){
      const int i = j*256 + tid, r = i / 48, c = i % 48;
      *(uix4*)(&sm.bt[r][c*8]) = *(const uix4*)(Uw16 + (size_t)i*8);
    }
  }
  __syncthreads();
  for (int t = 0; t < 16; ++t){
    uix4 pf[3];
    if (t < 15){
      const u16* src = Uw16 + (size_t)(t+1)*16*384;
      #pragma unroll
      for (int j = 0; j < 3; ++j)
        pf[j] = *(const uix4*)(src + (size_t)(j*256 + tid)*8);
    }
    f32x4 acc = {0.f, 0.f, 0.f, 0.f};
    const u16* bp = &sm.bt[m][q*8];
    #pragma unroll
    for (int j = 0; j < 12; ++j) acc = mfma16(A2[j], *(const uix4*)(bp + j*32), acc);
    const int c = t*16 + m;
    const float bias = Ub[c];
    const float uo   = Uo[c];
    #pragma unroll
    for (int i = 0; i < 4; ++i) sp[i] += fmaxf(acc[i] + bias, 0.f) * uo;
    __syncthreads();
    if (t < 15){
      #pragma unroll
      for (int j = 0; j < 3; ++j){
        const int i = j*256 + tid, r = i / 48, cc = i % 48;
        *(uix4*)(&sm.bt[r][cc*8]) = pf[j];
      }
      __syncthreads();
    }
  }
  #pragma unroll
  for (int msk = 1; msk < 16; msk <<= 1){
    #pragma unroll
    for (int i = 0; i < 4; ++i) sp[i] += __shfl_xor(sp[i], msk, 64);
  }
  if (m == 0){
    const float ub = Uob[0];
    #pragma unroll
    for (int i = 0; i < 4; ++i){
      const int r = r0 + q*4 + i;
      const float s   = sp[i] + ub;
      const float tgt = sm.tgt[r];
      sm.b0[r] = fmaxf(s, 0.f) - s * tgt + log1pf(__expf(-fabsf(s)));
      const float pb = (s >= 0.f) ? 1.f : 0.f;
      sm.b1[r] = (pb == tgt) ? 1.f : 0.f;
    }
  }
  __syncthreads();
  if (tid < 64){
    float a = sm.b0[tid], b = sm.b1[tid];
    #pragma unroll
    for (int off = 32; off > 0; off >>= 1){
      a += __shfl_down(a, off, 64); b += __shfl_down(b, off, 64);
    }
    if (tid == 0){ atomicAdd(&accum[3], a); atomicAdd(&accum[4], b); }
  }
}

__global__ __launch_bounds__(256, 3) void k_heads(
    const u16* __restrict__ hb16, const u16* __restrict__ emb16,
    const u16* __restrict__ Ww16, const float* __restrict__ Wb,
    const u16* __restrict__ Wo16, const float* __restrict__ Wob,
    const u16* __restrict__ Ui16, const float* __restrict__ Uib,
    const u16* __restrict__ Uw16, const float* __restrict__ Ub,
    const float* __restrict__ Uo, const float* __restrict__ Uob,
    const u16* __restrict__ xt16,
    const int* __restrict__ word_ids, const int* __restrict__ o_nei,
    const int* __restrict__ contexts, const int* __restrict__ pred_targets,
    const int* __restrict__ direction, const int* __restrict__ root_word_ids,
    const int* __restrict__ root_o_idx, float* __restrict__ accum)
{
  __shared__ __align__(16) char smraw[SMU_];
  const int b = blockIdx.x;
  if (b < PREDB_){
    pred_body(b, smraw, hb16, Ww16, Wb, Wo16, Wob, xt16,
              contexts, pred_targets, direction, root_word_ids, accum);
  } else {
    stop_body(b - PREDB_, smraw, hb16, emb16, Ui16, Uib, Uw16, Ub, Uo, Uob,
              xt16, word_ids, o_nei, contexts, direction,
              root_word_ids, root_o_idx, accum);
  }
}

// ---- finalize --------------------------------------------------------------
__global__ void k_final(const float* __restrict__ acc, float* __restrict__ out){
  if (threadIdx.x == 0 && blockIdx.x == 0){
    out[0] = acc[0] / (float)B_;               // pred_loss
    out[1] = acc[3] / (float)B_;               // stop_loss
    out[2] = acc[1] / acc[2];                  // pred_acc
    out[3] = acc[4] / (float)(E_ + B_);        // stop_acc
  }
}

} // anonymous namespace

extern "C" void kernel_launch(void* const* d_in, const int* in_sizes, int n_in,
                              void* d_out, int out_size, void* d_ws, size_t ws_size,
                              hipStream_t stream)
{
  const float* emb   = (const float*)d_in[0];
  const float* Wz    = (const float*)d_in[1];
  const float* Wzb   = (const float*)d_in[2];
  const float* Wr    = (const float*)d_in[3];
  const float* Wrb   = (const float*)d_in[4];
  const float* Ur    = (const float*)d_in[5];
  const float* Wh    = (const float*)d_in[6];
  const float* Whb   = (const float*)d_in[7];
  const float* Ww    = (const float*)d_in[8];
  const float* Wb    = (const float*)d_in[9];
  const float* Wo    = (const float*)d_in[10];
  const float* Wob   = (const float*)d_in[11];
  const float* Uw    = (const float*)d_in[12];
  const float* Ub    = (const float*)d_in[13];
  const float* Ui    = (const float*)d_in[14];
  const float* Uib   = (const float*)d_in[15];
  const float* Uo    = (const float*)d_in[16];
  const float* Uob   = (const float*)d_in[17];
  const float* xtree = (const float*)d_in[18];
  const int* word_ids      = (const int*)d_in[19];
  const int* h_nei_idx     = (const int*)d_in[20];
  const int* o_nei_idx     = (const int*)d_in[21];
  const int* contexts      = (const int*)d_in[22];
  const int* pred_targets  = (const int*)d_in[23];
  const int* direction     = (const int*)d_in[24];
  const int* root_word_ids = (const int*)d_in[25];
  const int* root_o_idx    = (const int*)d_in[26];

  char*  wsb   = (char*)d_ws;
  float* accum = (float*)wsb;
  size_t off = 256 + 4096;
  u16* hb16  = (u16*)(wsb + off); off += (size_t)(E_ + 1) * H_ * 2;  // 16.78 MB
  u16* emb16 = (u16*)(wsb + off); off += 204800u * 2;
  u16* xt16  = (u16*)(wsb + off); off += 32768u * 2;
  u16* Ww16  = (u16*)(wsb + off); off += 98304u * 2;
  u16* Wo16  = (u16*)(wsb + off); off += 204800u * 2;
  u16* Ui16  = (u16*)(wsb + off); off += 131072u * 2;
  u16* Uw16  = (u16*)(wsb + off); off += 98304u * 2;
  u16* Wz16  = (u16*)(wsb + off); off += 131072u * 2;
  u16* Wr16  = (u16*)(wsb + off); off += 65536u * 2;
  u16* Ur16  = (u16*)(wsb + off); off += 65536u * 2;
  u16* Wh16  = (u16*)(wsb + off); off += 131072u * 2;
  u16* UrF   = (u16*)(wsb + off); off += 65536u * 2;
  u16* WzF   = (u16*)(wsb + off); off += 65536u * 2;
  u16* WhF   = (u16*)(wsb + off); off += 65536u * 2;
  float* xrtab = (float*)(wsb + off); off += 204800u * 4;
  float* xztab = (float*)(wsb + off); off += 204800u * 4;
  float* xhtab = (float*)(wsb + off); off += 204800u * 4;
  float* out = (float*)d_out;

  hipLaunchKernelGGL(k_cvt, dim3(4544), dim3(256), 0, stream,
                     emb, xtree, Ww, Wo, Ui, Uw, Wz, Wr, Ur, Wh,
                     emb16, xt16, Ww16, Wo16, Ui16, Uw16,
                     Wz16, Wr16, Ur16, Wh16);
  hipLaunchKernelGGL(k_init, dim3(1), dim3(256), 0, stream, accum, hb16);
  hipLaunchKernelGGL(k_rep, dim3(96), dim3(256), 0, stream,
                     Ur16, Wz16, Wh16, UrF, WzF, WhF);
  hipLaunchKernelGGL(k_tab, dim3(50), dim3(256), 0, stream,
                     emb16, Wr16, Wrb, Wz16, Wzb, Wh16, Whb,
                     xrtab, xztab, xhtab);

  for (int t = 0; t < T_; ++t){
    hipLaunchKernelGGL(k_gru, dim3(N_), dim3(256), 0, stream,
                       UrF, WzF, WhF, xrtab, xztab, xhtab,
                       word_ids, h_nei_idx, hb16, t);
  }

  hipLaunchKernelGGL(k_heads, dim3(PREDB_ + STOPB_), dim3(256), 0, stream,
                     hb16, emb16, Ww16, Wb, Wo16, Wob, Ui16, Uib, Uw16, Ub,
                     Uo, Uob, xt16, word_ids, o_nei_idx, contexts,
                     pred_targets, direction, root_word_ids, root_o_idx,
                     accum);

  hipLaunchKernelGGL(k_final, dim3(1), dim3(1), 0, stream, accum, out);
}

// Round 14
// 578.804 us; speedup vs baseline: 1.3816x; 1.3816x over previous
//
#include <hip/hip_runtime.h>
#include <math.h>

// ---------------------------------------------------------------------------
// JTNN decoder forward on MI355X.  v14:
//  * Scan: reverted to v12 (4 rows/block, 1024 thr, grid 256, frag-major
//    weights) -- v13's 1-row/block quadrupled weight traffic (393MB/step)
//    and regressed; v12's 98MB/step at full CU coverage is the optimum.
//  * k_heads: (a) stop GEMM1 (Ui, K=512) now uses fragment-major UiF --
//    previously each wave streamed 256KB of Ui in uncoalesced per-lane 16B
//    reads (~528MB); now one coalesced 1KB wave-load per fragment.
//    (b) pred GEMM2 stages 2 tiles (32 cols) per LDS buffer: barrier pairs
//    50 -> 25, 2x MFMA per barrier.  3 blocks/CU preserved (PredSm 52KB).
//  * MFMA layouts (validated R2-R13): A[m=lane&15][k=32*kb+8*q+j],
//    B[k][n=lane&15], D[row=4*q+i][col=lane&15].
// ---------------------------------------------------------------------------

namespace {

constexpr int T_  = 32;
constexpr int N_  = 1024;
constexpr int H_  = 256;
constexpr int NB_ = 15;
constexpr int E_  = T_ * N_;      // 32768
constexpr int B_  = 256;
constexpr int PREDB_ = (B_ + E_) / 64;   // 516
constexpr int STOPB_ = (E_ + B_) / 64;   // 516

typedef unsigned short u16;
typedef unsigned int   u32;
typedef unsigned int  uix4  __attribute__((ext_vector_type(4)));
typedef __bf16        bf16x8 __attribute__((ext_vector_type(8)));
typedef float         f32x4  __attribute__((ext_vector_type(4)));

__device__ __forceinline__ float sig_(float x){ return 1.f / (1.f + __expf(-x)); }

__device__ __forceinline__ float b2f(u16 u){
  union { u32 i; float f; } v; v.i = ((u32)u) << 16; return v.f;
}
__device__ __forceinline__ u16 f2b(float f){
  union { float f; u32 i; } v; v.f = f;
  const u32 r = v.i + 0x7fffu + ((v.i >> 16) & 1u);
  return (u16)(r >> 16);
}
__device__ __forceinline__ f32x4 mfma16(uix4 a, uix4 b, f32x4 c){
  return __builtin_amdgcn_mfma_f32_16x16x32_bf16(
      __builtin_bit_cast(bf16x8, a), __builtin_bit_cast(bf16x8, b), c, 0, 0, 0);
}

// ---- fp32 -> bf16 conversion (once per launch) ----------------------------
__global__ __launch_bounds__(256) void k_cvt(
    const float* __restrict__ emb, const float* __restrict__ xt,
    const float* __restrict__ Ww,  const float* __restrict__ Wo,
    const float* __restrict__ Ui,  const float* __restrict__ Uw,
    const float* __restrict__ Wz,  const float* __restrict__ Wr,
    const float* __restrict__ Ur,  const float* __restrict__ Wh,
    u16* __restrict__ o_emb, u16* __restrict__ o_xt, u16* __restrict__ o_Ww,
    u16* __restrict__ o_Wo,  u16* __restrict__ o_Ui, u16* __restrict__ o_Uw,
    u16* __restrict__ o_Wz,  u16* __restrict__ o_Wr, u16* __restrict__ o_Ur,
    u16* __restrict__ o_Wh)
{
  int i = blockIdx.x * 256 + threadIdx.x;
  if (i < 204800){ o_emb[i] = f2b(emb[i]); return; }  i -= 204800;
  if (i <  32768){ o_xt[i]  = f2b(xt[i]);  return; }  i -=  32768;
  if (i <  98304){ o_Ww[i]  = f2b(Ww[i]);  return; }  i -=  98304;
  if (i < 204800){ o_Wo[i]  = f2b(Wo[i]);  return; }  i -= 204800;
  if (i < 131072){ o_Ui[i]  = f2b(Ui[i]);  return; }  i -= 131072;
  if (i <  98304){ o_Uw[i]  = f2b(Uw[i]);  return; }  i -=  98304;
  if (i < 131072){ o_Wz[i]  = f2b(Wz[i]);  return; }  i -= 131072;
  if (i <  65536){ o_Wr[i]  = f2b(Wr[i]);  return; }  i -=  65536;
  if (i <  65536){ o_Ur[i]  = f2b(Ur[i]);  return; }  i -=  65536;
  if (i < 131072){ o_Wh[i]  = f2b(Wh[i]); }
}

// ---- fragment-major repack: Ur, Wz sum_h-half, Wh gated-half, Ui ----------
__global__ __launch_bounds__(256) void k_rep(
    const u16* __restrict__ Ur16, const u16* __restrict__ Wz16,
    const u16* __restrict__ Wh16, const u16* __restrict__ Ui16,
    u16* __restrict__ UrF, u16* __restrict__ WzF, u16* __restrict__ WhF,
    u16* __restrict__ UiF)
{
  const int idx = blockIdx.x * 256 + threadIdx.x;
  if (idx < 24576){                      // K=256 matrices: 3 x 8192 chunks
    const int mat = idx >> 13, r = idx & 8191;
    const int ctkb = r >> 6, lane = r & 63;
    const int ct = ctkb >> 3, kb = ctkb & 7;
    const int q = lane >> 4, m = lane & 15;
    const int col = ct * 16 + m;
    const u16* src;
    u16* dst;
    if (mat == 0){ src = Ur16 + (size_t)col*256 +       kb*32 + q*8; dst = UrF; }
    else if (mat == 1){ src = Wz16 + (size_t)col*512 + 256 + kb*32 + q*8; dst = WzF; }
    else { src = Wh16 + (size_t)col*512 + 256 + kb*32 + q*8; dst = WhF; }
    *(uix4*)(dst + (size_t)r * 8) = *(const uix4*)src;
  } else {                               // Ui (K=512): 16384 chunks
    const int r = idx - 24576;
    if (r >= 16384) return;
    const int ctkb = r >> 6, lane = r & 63;
    const int ct = ctkb >> 4, kb = ctkb & 15;
    const int q = lane >> 4, m = lane & 15;
    const int col = ct * 16 + m;
    *(uix4*)(UiF + (size_t)r * 8) =
        *(const uix4*)(Ui16 + (size_t)col*512 + kb*32 + q*8);
  }
}

// ---- init ------------------------------------------------------------------
__global__ __launch_bounds__(256) void k_init(float* __restrict__ acc,
                                              u16* __restrict__ hb16){
  const int tid = threadIdx.x;
  if (tid < 16) acc[tid] = 0.f;
  hb16[(size_t)E_ * H_ + tid] = 0;   // row E = zero pad slot
}

// ---- precompute x-side gate tables: 800x256 fp32, bias folded -------------
__global__ __launch_bounds__(256) void k_tab(
    const u16* __restrict__ emb16,
    const u16* __restrict__ Wr16, const float* __restrict__ Wrb,
    const u16* __restrict__ Wz16, const float* __restrict__ Wzb,
    const u16* __restrict__ Wh16, const float* __restrict__ Whb,
    float* __restrict__ xrtab, float* __restrict__ xztab,
    float* __restrict__ xhtab)
{
  const int tid = threadIdx.x;
  const int w = tid >> 6, ln = tid & 63, q = ln >> 4, m = ln & 15;
  const int r0 = blockIdx.x * 16;

  uix4 Ae[8];
  {
    const u16* ep = emb16 + (size_t)(r0 + m) * 256 + q * 8;
    #pragma unroll
    for (int kb = 0; kb < 8; ++kb) Ae[kb] = *(const uix4*)(ep + kb * 32);
  }
  #pragma unroll
  for (int nt = 0; nt < 4; ++nt){
    const int col = w * 64 + nt * 16 + m;
    f32x4 ar = {0.f,0.f,0.f,0.f}, az = {0.f,0.f,0.f,0.f}, ah = {0.f,0.f,0.f,0.f};
    const u16* br = Wr16 + (size_t)col * 256 + q * 8;
    const u16* bz = Wz16 + (size_t)col * 512 + q * 8;   // x-part of Wz
    const u16* bh = Wh16 + (size_t)col * 512 + q * 8;   // x-part of Wh
    #pragma unroll
    for (int kb = 0; kb < 8; ++kb){
      ar = mfma16(Ae[kb], *(const uix4*)(br + kb*32), ar);
      az = mfma16(Ae[kb], *(const uix4*)(bz + kb*32), az);
      ah = mfma16(Ae[kb], *(const uix4*)(bh + kb*32), ah);
    }
    const float rb = Wrb[col], zb = Wzb[col], hb = Whb[col];
    #pragma unroll
    for (int i = 0; i < 4; ++i){
      const size_t o = (size_t)(r0 + 4*q + i) * 256 + col;
      xrtab[o] = ar[i] + rb;
      xztab[o] = az[i] + zb;
      xhtab[o] = ah[i] + hb;
    }
  }
}

// ---- one GRU scan step (v12 validated): 4 rows/block, 1024 thr, grid 256 --
__global__ __launch_bounds__(1024, 4) void k_gru(
    const u16* __restrict__ UrF, const u16* __restrict__ WzF,
    const u16* __restrict__ WhF,
    const float* __restrict__ xrtab, const float* __restrict__ xztab,
    const float* __restrict__ xhtab,
    const int* __restrict__ word_ids, const int* __restrict__ h_nei,
    u16* __restrict__ hb16, int t)
{
  __shared__ __align__(16) u16 hn[64 * 264];   // 64 (row,nb) pairs, padded
  __shared__ __align__(16) u16 sh[4][264];     // sum_h (A-layout)
  __shared__ __align__(16) u16 gl[4][264];     // gated (A-layout)
  __shared__ int s_wid[4];
  __shared__ int s_hidx[64];                   // pair p = nb*4 + row

  const int tid = threadIdx.x;
  const int w = tid >> 6, ln = tid & 63, q = ln >> 4, m = ln & 15;
  const int col  = w * 16 + m;                 // this wave-lane's output col
  const int base = t * N_ + blockIdx.x * 4;    // first message row

  if (tid < 4) s_wid[tid] = word_ids[base + tid];
  if (tid < 64){
    const int row = tid & 3, nb = tid >> 2;
    s_hidx[tid] = (nb < NB_) ? h_nei[(base + row) * NB_ + nb] : E_;
  }

  // batch-load Ur B-frags (coalesced 1KB wave loads, named regs)
  const u16* urb = UrF + (size_t)(w * 8) * 512 + ln * 8;
  uix4 b0 = *(const uix4*)(urb);
  uix4 b1 = *(const uix4*)(urb + 512);
  uix4 b2 = *(const uix4*)(urb + 1024);
  uix4 b3 = *(const uix4*)(urb + 1536);
  uix4 b4 = *(const uix4*)(urb + 2048);
  uix4 b5 = *(const uix4*)(urb + 2560);
  uix4 b6 = *(const uix4*)(urb + 3072);
  uix4 b7 = *(const uix4*)(urb + 3584);

  __syncthreads();

  // stage 64 pair-rows (512B coalesced each)
  #pragma unroll
  for (int it = 0; it < 2; ++it){
    const int task = it * 1024 + tid;
    const int row = task >> 5, ch = task & 31;
    *(uix4*)(&hn[row*264 + ch*8]) =
        *(const uix4*)(hb16 + (size_t)s_hidx[row]*256 + ch*8);
  }
  __syncthreads();

  // xr C-init from table (D row 4q+i == msg i; bias folded)
  f32x4 xr;
  #pragma unroll
  for (int i = 0; i < 4; ++i) xr[i] = xrtab[(size_t)s_wid[i] * 256 + col];

  // r-gate GEMM over 4 pair-tiles
  float ga[4] = {0.f,0.f,0.f,0.f}, su[4] = {0.f,0.f,0.f,0.f};
  #pragma unroll
  for (int j = 0; j < 4; ++j){
    uix4 Ah[8];
    #pragma unroll
    for (int kb = 0; kb < 8; ++kb)
      Ah[kb] = *(const uix4*)(&hn[(j*16 + m)*264 + kb*32 + q*8]);
    f32x4 a = xr;
    a = mfma16(Ah[0], b0, a); a = mfma16(Ah[1], b1, a);
    a = mfma16(Ah[2], b2, a); a = mfma16(Ah[3], b3, a);
    a = mfma16(Ah[4], b4, a); a = mfma16(Ah[5], b5, a);
    a = mfma16(Ah[6], b6, a); a = mfma16(Ah[7], b7, a);
    #pragma unroll
    for (int i = 0; i < 4; ++i){
      const float hv = b2f(hn[(j*16 + 4*q + i)*264 + col]);
      ga[i] += sig_(a[i]) * hv;
      su[i] += hv;
    }
  }

  // reduce over nb partition (quads): nb = 4j+q -> sum over q
  #pragma unroll
  for (int i = 0; i < 4; ++i){
    ga[i] += __shfl_xor(ga[i], 16, 64);
    ga[i] += __shfl_xor(ga[i], 32, 64);
    su[i] += __shfl_xor(su[i], 16, 64);
    su[i] += __shfl_xor(su[i], 32, 64);
  }
  if (q == 0){
    #pragma unroll
    for (int i = 0; i < 4; ++i){
      sh[i][col] = f2b(su[i]);
      gl[i][col] = f2b(ga[i]);
    }
  }
  __syncthreads();

  // z / h~ GEMMs (K=256, C-init from tables), B-frags batch-loaded
  f32x4 az, ah;
  #pragma unroll
  for (int i = 0; i < 4; ++i){
    az[i] = xztab[(size_t)s_wid[i] * 256 + col];
    ah[i] = xhtab[(size_t)s_wid[i] * 256 + col];
  }
  {
    const u16* zb = WzF + (size_t)(w * 8) * 512 + ln * 8;
    uix4 Bz[8];
    #pragma unroll
    for (int kb = 0; kb < 8; ++kb) Bz[kb] = *(const uix4*)(zb + kb * 512);
    uix4 As[8];
    #pragma unroll
    for (int kb = 0; kb < 8; ++kb) As[kb] = *(const uix4*)(&sh[m & 3][kb*32 + q*8]);
    #pragma unroll
    for (int kb = 0; kb < 8; ++kb) az = mfma16(As[kb], Bz[kb], az);
  }
  {
    const u16* hb = WhF + (size_t)(w * 8) * 512 + ln * 8;
    uix4 Bh[8];
    #pragma unroll
    for (int kb = 0; kb < 8; ++kb) Bh[kb] = *(const uix4*)(hb + kb * 512);
    uix4 Ag[8];
    #pragma unroll
    for (int kb = 0; kb < 8; ++kb) Ag[kb] = *(const uix4*)(&gl[m & 3][kb*32 + q*8]);
    #pragma unroll
    for (int kb = 0; kb < 8; ++kb) ah = mfma16(Ag[kb], Bh[kb], ah);
  }
  if (q == 0){
    #pragma unroll
    for (int i = 0; i < 4; ++i){
      const float z  = sig_(az[i]);
      const float ht = tanhf(ah[i]);
      const float nh = (1.f - z) * su[i] + z * ht;
      hb16[(size_t)(base + i) * 256 + col] = f2b(nh);
    }
  }
}

// ---- merged heads ----------------------------------------------------------
struct PredSm {
  u16   hd[4][16][264];   // relu'd hidden per wave
  u16   bt[32 * 264];     // flat B-tile region (GEMM1: 16x392; GEMM2: 32x264)
  int   tgt[64];
  float mask[64];
  float nll[64], hit[64], msk[64];
};
struct StopSm {
  u16   so[64][264];
  u16   bt[16 * 392];
  int   oidx[64][NB_];
  int   wid[64], ctx[64];
  float tgt[64];
  float b0[64], b1[64];
};
constexpr size_t SMU_ = sizeof(StopSm) > sizeof(PredSm) ? sizeof(StopSm)
                                                        : sizeof(PredSm);

__device__ void pred_body(int bid, char* smraw,
    const u16* __restrict__ hb16, const u16* __restrict__ Ww16,
    const float* __restrict__ Wb, const u16* __restrict__ Wo16,
    const float* __restrict__ Wob, const u16* __restrict__ xt16,
    const int* __restrict__ contexts, const int* __restrict__ pred_targets,
    const int* __restrict__ direction, const int* __restrict__ root_word_ids,
    float* __restrict__ accum)
{
  PredSm& sm = *(PredSm*)smraw;
  const int tid = threadIdx.x;
  const int p0  = bid * 64;
  const int w = tid >> 6, ln = tid & 63, q = ln >> 4, m = ln & 15;
  const int r0 = w * 16;

  if (tid < 64){
    const int p = p0 + tid;
    int tg; float mk;
    if (p < B_){ tg = root_word_ids[p]; mk = 1.f; }
    else { tg = pred_targets[p - B_]; mk = (float)direction[p - B_]; }
    sm.tgt[tid] = tg; sm.mask[tid] = mk;
  }
  const int p    = p0 + r0 + m;
  const int hrow = (p < B_) ? E_ : (p - B_);
  const int ctx  = (p < B_) ? p  : contexts[p - B_];

  uix4 A1[12];
  {
    const u16* hp = hb16 + (size_t)hrow * 256 + q * 8;
    #pragma unroll
    for (int j = 0; j < 8; ++j) A1[j] = *(const uix4*)(hp + j * 32);
    const u16* xp = xt16 + (size_t)ctx * 128 + q * 8;
    #pragma unroll
    for (int j = 0; j < 4; ++j) A1[8 + j] = *(const uix4*)(xp + j * 32);
  }

  // GEMM1: hid = relu([h|xt] @ Ww^T + Wb), single-buffer LDS tiles (16x392)
  {
    #pragma unroll
    for (int j = 0; j < 3; ++j){
      const int i = j*256 + tid, r = i / 48, c = i % 48;
      *(uix4*)(&sm.bt[r*392 + c*8]) = *(const uix4*)(Ww16 + (size_t)i*8);
    }
  }
  __syncthreads();
  for (int t = 0; t < 16; ++t){
    uix4 pf[3];
    if (t < 15){
      const u16* src = Ww16 + (size_t)(t+1)*16*384;
      #pragma unroll
      for (int j = 0; j < 3; ++j)
        pf[j] = *(const uix4*)(src + (size_t)(j*256 + tid)*8);
    }
    f32x4 acc = {0.f, 0.f, 0.f, 0.f};
    const u16* bp = &sm.bt[m*392 + q*8];
    #pragma unroll
    for (int j = 0; j < 12; ++j) acc = mfma16(A1[j], *(const uix4*)(bp + j*32), acc);
    const float bias = Wb[t*16 + m];
    #pragma unroll
    for (int i = 0; i < 4; ++i)
      sm.hd[w][q*4 + i][t*16 + m] = f2b(fmaxf(acc[i] + bias, 0.f));
    __syncthreads();
    if (t < 15){
      #pragma unroll
      for (int j = 0; j < 3; ++j){
        const int i = j*256 + tid, r = i / 48, c = i % 48;
        *(uix4*)(&sm.bt[r*392 + c*8]) = pf[j];
      }
      __syncthreads();
    }
  }

  // GEMM2: 2 tiles (32 cols) per LDS buffer -> 25 phases instead of 50
  uix4 A2[8];
  #pragma unroll
  for (int j = 0; j < 8; ++j) A2[j] = *(const uix4*)(&sm.hd[w][m][j*32 + q*8]);

  int tgtc[4];
  #pragma unroll
  for (int i = 0; i < 4; ++i) tgtc[i] = sm.tgt[r0 + q*4 + i];
  float lrun[4], amax[4], tval[4]; int aidx[4];
  #pragma unroll
  for (int i = 0; i < 4; ++i){
    lrun[i] = 0.f; amax[i] = -1e30f; tval[i] = -1e30f; aidx[i] = 0;
  }

  {
    #pragma unroll
    for (int j = 0; j < 4; ++j){
      const int i = j*256 + tid, r = i >> 5, c = i & 31;
      *(uix4*)(&sm.bt[r*264 + c*8]) = *(const uix4*)(Wo16 + (size_t)i*8);
    }
  }
  __syncthreads();
  for (int pp = 0; pp < 25; ++pp){
    uix4 pf[4];
    if (pp < 24){
      const u16* src = Wo16 + (size_t)(pp+1)*32*256;
      #pragma unroll
      for (int j = 0; j < 4; ++j)
        pf[j] = *(const uix4*)(src + (size_t)(j*256 + tid)*8);
    }
    f32x4 a0 = {0.f,0.f,0.f,0.f}, a1 = {0.f,0.f,0.f,0.f};
    const u16* bp0 = &sm.bt[m*264 + q*8];
    const u16* bp1 = &sm.bt[(16 + m)*264 + q*8];
    #pragma unroll
    for (int j = 0; j < 8; ++j){
      a0 = mfma16(A2[j], *(const uix4*)(bp0 + j*32), a0);
      a1 = mfma16(A2[j], *(const uix4*)(bp1 + j*32), a1);
    }
    const int c0 = pp*32 + m, c1 = c0 + 16;
    const float bias0 = Wob[c0], bias1 = Wob[c1];
    #pragma unroll
    for (int i = 0; i < 4; ++i){
      const float v0 = a0[i] + bias0;
      const float v1 = a1[i] + bias1;
      if (c0 == tgtc[i]) tval[i] = v0;
      if (c1 == tgtc[i]) tval[i] = v1;
      if (v0 > amax[i]){ amax[i] = v0; aidx[i] = c0; }
      if (v1 > amax[i]){ amax[i] = v1; aidx[i] = c1; }
      lrun[i] += __expf(v0) + __expf(v1);
    }
    __syncthreads();
    if (pp < 24){
      #pragma unroll
      for (int j = 0; j < 4; ++j){
        const int i = j*256 + tid, r = i >> 5, cc = i & 31;
        *(uix4*)(&sm.bt[r*264 + cc*8]) = pf[j];
      }
      __syncthreads();
    }
  }
  #pragma unroll
  for (int msk = 1; msk < 16; msk <<= 1){
    #pragma unroll
    for (int i = 0; i < 4; ++i){
      lrun[i] += __shfl_xor(lrun[i], msk, 64);
      const float oa = __shfl_xor(amax[i], msk, 64);
      const int   oi = __shfl_xor(aidx[i], msk, 64);
      if (oa > amax[i] || (oa == amax[i] && oi < aidx[i])){ amax[i] = oa; aidx[i] = oi; }
      tval[i] = fmaxf(tval[i], __shfl_xor(tval[i], msk, 64));
    }
  }
  if (m == 0){
    #pragma unroll
    for (int i = 0; i < 4; ++i){
      const int r = r0 + q*4 + i;
      const float mk  = sm.mask[r];
      const float nll = __logf(lrun[i]) - tval[i];
      sm.nll[r] = nll * mk;
      sm.hit[r] = (aidx[i] == tgtc[i]) ? mk : 0.f;
      sm.msk[r] = mk;
    }
  }
  __syncthreads();
  if (tid < 64){
    float a = sm.nll[tid], b = sm.hit[tid], c2 = sm.msk[tid];
    #pragma unroll
    for (int off = 32; off > 0; off >>= 1){
      a += __shfl_down(a, off, 64); b += __shfl_down(b, off, 64); c2 += __shfl_down(c2, off, 64);
    }
    if (tid == 0){
      atomicAdd(&accum[0], a); atomicAdd(&accum[1], b); atomicAdd(&accum[2], c2);
    }
  }
}

__device__ void stop_body(int bid, char* smraw,
    const u16* __restrict__ hb16, const u16* __restrict__ emb16,
    const u16* __restrict__ UiF,  const float* __restrict__ Uib,
    const u16* __restrict__ Uw16, const float* __restrict__ Ub,
    const float* __restrict__ Uo, const float* __restrict__ Uob,
    const u16* __restrict__ xt16,
    const int* __restrict__ word_ids, const int* __restrict__ o_nei,
    const int* __restrict__ contexts, const int* __restrict__ direction,
    const int* __restrict__ root_word_ids, const int* __restrict__ root_o_idx,
    float* __restrict__ accum)
{
  StopSm& sm = *(StopSm*)smraw;
  const int tid = threadIdx.x;
  const int p0  = bid * 64;
  const int w = tid >> 6, ln = tid & 63, q = ln >> 4, m = ln & 15;
  const int r0 = w * 16;

  if (tid < 64){
    const int s = p0 + tid;
    if (s < E_){ sm.wid[tid] = word_ids[s]; sm.ctx[tid] = contexts[s];
                 sm.tgt[tid] = (float)direction[s]; }
    else { const int b = s - E_; sm.wid[tid] = root_word_ids[b]; sm.ctx[tid] = b;
           sm.tgt[tid] = 0.f; }
  }
  for (int k = tid; k < 64 * NB_; k += 256){
    const int r = k / NB_, nb = k % NB_;
    const int s = p0 + r;
    sm.oidx[r][nb] = (s < E_) ? o_nei[(size_t)s * NB_ + nb]
                              : root_o_idx[(size_t)(s - E_) * NB_ + nb];
  }
  __syncthreads();

  // stage sum_o: task-parallel (row, 16-col slice), coalesced uix4 gathers
  for (int it = 0; it < 4; ++it){
    const int task = it * 256 + tid;
    const int row = task >> 4, sl = task & 15;
    float a[16];
    #pragma unroll
    for (int c = 0; c < 16; ++c) a[c] = 0.f;
    #pragma unroll
    for (int nb = 0; nb < NB_; ++nb){
      const u16* p = hb16 + (size_t)sm.oidx[row][nb] * 256 + sl * 16;
      const uix4 v0 = *(const uix4*)(p);
      const uix4 v1 = *(const uix4*)(p + 8);
      #pragma unroll
      for (int c = 0; c < 4; ++c){
        a[2*c]     += b2f((u16)(v0[c] & 0xffffu));
        a[2*c + 1] += b2f((u16)(v0[c] >> 16));
        a[8 + 2*c] += b2f((u16)(v1[c] & 0xffffu));
        a[9 + 2*c] += b2f((u16)(v1[c] >> 16));
      }
    }
    uix4 o0, o1;
    #pragma unroll
    for (int c = 0; c < 4; ++c){
      o0[c] = (u32)f2b(a[2*c])   | ((u32)f2b(a[2*c+1]) << 16);
      o1[c] = (u32)f2b(a[8+2*c]) | ((u32)f2b(a[9+2*c]) << 16);
    }
    *(uix4*)(&sm.so[row][sl*16])     = o0;
    *(uix4*)(&sm.so[row][sl*16 + 8]) = o1;
  }
  __syncthreads();

  // A for GEMM1: [emb | sum_o]  (K = 512)
  uix4 A1[16];
  {
    const u16* ep = emb16 + (size_t)sm.wid[r0 + m] * 256 + q * 8;
    #pragma unroll
    for (int j = 0; j < 8; ++j) A1[j] = *(const uix4*)(ep + j * 32);
    #pragma unroll
    for (int j = 0; j < 8; ++j) A1[8 + j] = *(const uix4*)(&sm.so[r0 + m][j*32 + q*8]);
  }
  __syncthreads();   // all waves captured so -> safe to overwrite with h1

  // GEMM1: h1 = relu(inp @ Ui^T + Uib), fragment-major UiF (coalesced)
  for (int t = 0; t < 16; ++t){
    const u16* bp = UiF + (size_t)(t * 16) * 512 + ln * 8;
    uix4 Bf[16];
    #pragma unroll
    for (int kb = 0; kb < 16; ++kb) Bf[kb] = *(const uix4*)(bp + kb * 512);
    f32x4 acc = {0.f, 0.f, 0.f, 0.f};
    #pragma unroll
    for (int kb = 0; kb < 16; ++kb) acc = mfma16(A1[kb], Bf[kb], acc);
    const float bias = Uib[t*16 + m];
    #pragma unroll
    for (int i = 0; i < 4; ++i)
      sm.so[r0 + q*4 + i][t*16 + m] = f2b(fmaxf(acc[i] + bias, 0.f));
  }
  __syncthreads();

  // GEMM2: h2 = relu([h1|xt] @ Uw^T + Ub); s = h2.Uo + Uob; LDS B tiles
  uix4 A2[12];
  {
    #pragma unroll
    for (int j = 0; j < 8; ++j) A2[j] = *(const uix4*)(&sm.so[r0 + m][j*32 + q*8]);
    const u16* xp = xt16 + (size_t)sm.ctx[r0 + m] * 128 + q * 8;
    #pragma unroll
    for (int j = 0; j < 4; ++j) A2[8 + j] = *(const uix4*)(xp + j * 32);
  }
  float sp[4] = {0.f, 0.f, 0.f, 0.f};
  {
    #pragma unroll
    for (int j = 0; j < 3; ++j){
      const int i = j*256 + tid, r = i / 48, c = i % 48;
      *(uix4*)(&sm.bt[r*392 + c*8]) = *(const uix4*)(Uw16 + (size_t)i*8);
    }
  }
  __syncthreads();
  for (int t = 0; t < 16; ++t){
    uix4 pf[3];
    if (t < 15){
      const u16* src = Uw16 + (size_t)(t+1)*16*384;
      #pragma unroll
      for (int j = 0; j < 3; ++j)
        pf[j] = *(const uix4*)(src + (size_t)(j*256 + tid)*8);
    }
    f32x4 acc = {0.f, 0.f, 0.f, 0.f};
    const u16* bp = &sm.bt[m*392 + q*8];
    #pragma unroll
    for (int j = 0; j < 12; ++j) acc = mfma16(A2[j], *(const uix4*)(bp + j*32), acc);
    const int c = t*16 + m;
    const float bias = Ub[c];
    const float uo   = Uo[c];
    #pragma unroll
    for (int i = 0; i < 4; ++i) sp[i] += fmaxf(acc[i] + bias, 0.f) * uo;
    __syncthreads();
    if (t < 15){
      #pragma unroll
      for (int j = 0; j < 3; ++j){
        const int i = j*256 + tid, r = i / 48, cc = i % 48;
        *(uix4*)(&sm.bt[r*392 + cc*8]) = pf[j];
      }
      __syncthreads();
    }
  }
  #pragma unroll
  for (int msk = 1; msk < 16; msk <<= 1){
    #pragma unroll
    for (int i = 0; i < 4; ++i) sp[i] += __shfl_xor(sp[i], msk, 64);
  }
  if (m == 0){
    const float ub = Uob[0];
    #pragma unroll
    for (int i = 0; i < 4; ++i){
      const int r = r0 + q*4 + i;
      const float s   = sp[i] + ub;
      const float tgt = sm.tgt[r];
      sm.b0[r] = fmaxf(s, 0.f) - s * tgt + log1pf(__expf(-fabsf(s)));
      const float pb = (s >= 0.f) ? 1.f : 0.f;
      sm.b1[r] = (pb == tgt) ? 1.f : 0.f;
    }
  }
  __syncthreads();
  if (tid < 64){
    float a = sm.b0[tid], b = sm.b1[tid];
    #pragma unroll
    for (int off = 32; off > 0; off >>= 1){
      a += __shfl_down(a, off, 64); b += __shfl_down(b, off, 64);
    }
    if (tid == 0){ atomicAdd(&accum[3], a); atomicAdd(&accum[4], b); }
  }
}

__global__ __launch_bounds__(256, 3) void k_heads(
    const u16* __restrict__ hb16, const u16* __restrict__ emb16,
    const u16* __restrict__ Ww16, const float* __restrict__ Wb,
    const u16* __restrict__ Wo16, const float* __restrict__ Wob,
    const u16* __restrict__ UiF,  const float* __restrict__ Uib,
    const u16* __restrict__ Uw16, const float* __restrict__ Ub,
    const float* __restrict__ Uo, const float* __restrict__ Uob,
    const u16* __restrict__ xt16,
    const int* __restrict__ word_ids, const int* __restrict__ o_nei,
    const int* __restrict__ contexts, const int* __restrict__ pred_targets,
    const int* __restrict__ direction, const int* __restrict__ root_word_ids,
    const int* __restrict__ root_o_idx, float* __restrict__ accum)
{
  __shared__ __align__(16) char smraw[SMU_];
  const int b = blockIdx.x;
  if (b < PREDB_){
    pred_body(b, smraw, hb16, Ww16, Wb, Wo16, Wob, xt16,
              contexts, pred_targets, direction, root_word_ids, accum);
  } else {
    stop_body(b - PREDB_, smraw, hb16, emb16, UiF, Uib, Uw16, Ub, Uo, Uob,
              xt16, word_ids, o_nei, contexts, direction,
              root_word_ids, root_o_idx, accum);
  }
}

// ---- finalize --------------------------------------------------------------
__global__ void k_final(const float* __restrict__ acc, float* __restrict__ out){
  if (threadIdx.x == 0 && blockIdx.x == 0){
    out[0] = acc[0] / (float)B_;               // pred_loss
    out[1] = acc[3] / (float)B_;               // stop_loss
    out[2] = acc[1] / acc[2];                  // pred_acc
    out[3] = acc[4] / (float)(E_ + B_);        // stop_acc
  }
}

} // anonymous namespace

extern "C" void kernel_launch(void* const* d_in, const int* in_sizes, int n_in,
                              void* d_out, int out_size, void* d_ws, size_t ws_size,
                              hipStream_t stream)
{
  const float* emb   = (const float*)d_in[0];
  const float* Wz    = (const float*)d_in[1];
  const float* Wzb   = (const float*)d_in[2];
  const float* Wr    = (const float*)d_in[3];
  const float* Wrb   = (const float*)d_in[4];
  const float* Ur    = (const float*)d_in[5];
  const float* Wh    = (const float*)d_in[6];
  const float* Whb   = (const float*)d_in[7];
  const float* Ww    = (const float*)d_in[8];
  const float* Wb    = (const float*)d_in[9];
  const float* Wo    = (const float*)d_in[10];
  const float* Wob   = (const float*)d_in[11];
  const float* Uw    = (const float*)d_in[12];
  const float* Ub    = (const float*)d_in[13];
  const float* Ui    = (const float*)d_in[14];
  const float* Uib   = (const float*)d_in[15];
  const float* Uo    = (const float*)d_in[16];
  const float* Uob   = (const float*)d_in[17];
  const float* xtree = (const float*)d_in[18];
  const int* word_ids      = (const int*)d_in[19];
  const int* h_nei_idx     = (const int*)d_in[20];
  const int* o_nei_idx     = (const int*)d_in[21];
  const int* contexts      = (const int*)d_in[22];
  const int* pred_targets  = (const int*)d_in[23];
  const int* direction     = (const int*)d_in[24];
  const int* root_word_ids = (const int*)d_in[25];
  const int* root_o_idx    = (const int*)d_in[26];

  char*  wsb   = (char*)d_ws;
  float* accum = (float*)wsb;
  size_t off = 256 + 4096;
  u16* hb16  = (u16*)(wsb + off); off += (size_t)(E_ + 1) * H_ * 2;  // 16.78 MB
  u16* emb16 = (u16*)(wsb + off); off += 204800u * 2;
  u16* xt16  = (u16*)(wsb + off); off += 32768u * 2;
  u16* Ww16  = (u16*)(wsb + off); off += 98304u * 2;
  u16* Wo16  = (u16*)(wsb + off); off += 204800u * 2;
  u16* Ui16  = (u16*)(wsb + off); off += 131072u * 2;
  u16* Uw16  = (u16*)(wsb + off); off += 98304u * 2;
  u16* Wz16  = (u16*)(wsb + off); off += 131072u * 2;
  u16* Wr16  = (u16*)(wsb + off); off += 65536u * 2;
  u16* Ur16  = (u16*)(wsb + off); off += 65536u * 2;
  u16* Wh16  = (u16*)(wsb + off); off += 131072u * 2;
  u16* UrF   = (u16*)(wsb + off); off += 65536u * 2;
  u16* WzF   = (u16*)(wsb + off); off += 65536u * 2;
  u16* WhF   = (u16*)(wsb + off); off += 65536u * 2;
  u16* UiF   = (u16*)(wsb + off); off += 131072u * 2;
  float* xrtab = (float*)(wsb + off); off += 204800u * 4;
  float* xztab = (float*)(wsb + off); off += 204800u * 4;
  float* xhtab = (float*)(wsb + off); off += 204800u * 4;
  float* out = (float*)d_out;

  hipLaunchKernelGGL(k_cvt, dim3(4544), dim3(256), 0, stream,
                     emb, xtree, Ww, Wo, Ui, Uw, Wz, Wr, Ur, Wh,
                     emb16, xt16, Ww16, Wo16, Ui16, Uw16,
                     Wz16, Wr16, Ur16, Wh16);
  hipLaunchKernelGGL(k_init, dim3(1), dim3(256), 0, stream, accum, hb16);
  hipLaunchKernelGGL(k_rep, dim3(160), dim3(256), 0, stream,
                     Ur16, Wz16, Wh16, Ui16, UrF, WzF, WhF, UiF);
  hipLaunchKernelGGL(k_tab, dim3(50), dim3(256), 0, stream,
                     emb16, Wr16, Wrb, Wz16, Wzb, Wh16, Whb,
                     xrtab, xztab, xhtab);

  for (int t = 0; t < T_; ++t){
    hipLaunchKernelGGL(k_gru, dim3(N_ / 4), dim3(1024), 0, stream,
                       UrF, WzF, WhF, xrtab, xztab, xhtab,
                       word_ids, h_nei_idx, hb16, t);
  }

  hipLaunchKernelGGL(k_heads, dim3(PREDB_ + STOPB_), dim3(256), 0, stream,
                     hb16, emb16, Ww16, Wb, Wo16, Wob, UiF, Uib, Uw16, Ub,
                     Uo, Uob, xt16, word_ids, o_nei_idx, contexts,
                     pred_targets, direction, root_word_ids, root_o_idx,
                     accum);

  hipLaunchKernelGGL(k_final, dim3(1), dim3(1), 0, stream, accum, out);
}